// Round 8
// baseline (550.067 us; speedup 1.0000x reference)
//
#include <hip/hip_runtime.h>

typedef __attribute__((ext_vector_type(4))) float f32x4;
typedef __attribute__((ext_vector_type(8))) _Float16 f16x8;
typedef __attribute__((ext_vector_type(4))) unsigned short u16x4;
typedef __attribute__((ext_vector_type(8))) unsigned short u16x8;

#define NB 4096
#define NS 6
#define NC 2048
#define MTOT (NB * NS)   // 24576

static __device__ __forceinline__ unsigned short f2h_bits(float f) {
  _Float16 h = (_Float16)f;
  unsigned short b;
  __builtin_memcpy(&b, &h, 2);
  return b;
}
static __device__ __forceinline__ float h2f(unsigned short b) {
  _Float16 h;
  __builtin_memcpy(&h, &b, 2);
  return (float)h;
}

// ---------------- prep kernels ----------------
__global__ void split_x_kernel(const float* __restrict__ x,
                               unsigned short* __restrict__ hi,
                               unsigned short* __restrict__ lo, int n4) {
  int i = blockIdx.x * blockDim.x + threadIdx.x;
  const int stride = gridDim.x * blockDim.x;
  for (; i < n4; i += stride) {
    f32x4 v = reinterpret_cast<const f32x4*>(x)[i];
    u16x4 h, l;
#pragma unroll
    for (int j = 0; j < 4; ++j) {
      const unsigned short hb = f2h_bits(v[j]);
      h[j] = hb;
      l[j] = f2h_bits(v[j] - h2f(hb));
    }
    reinterpret_cast<u16x4*>(hi)[i] = h;
    reinterpret_cast<u16x4*>(lo)[i] = l;
  }
}

__global__ void prep_wqk_kernel(const float* __restrict__ Wq,
                                const float* __restrict__ Wk,
                                unsigned short* __restrict__ w) {
  int i = blockIdx.x * blockDim.x + threadIdx.x;
  const int stride = gridDim.x * blockDim.x;
  for (; i < 262144; i += stride) {
    const int row = i >> 9;
    const int col4 = i & 511;
    const float* src = (row < 256) ? (Wq + (size_t)row * NC)
                                   : (Wk + (size_t)(row - 256) * NC);
    f32x4 v = reinterpret_cast<const f32x4*>(src)[col4];
    u16x4 o;
#pragma unroll
    for (int j = 0; j < 4; ++j) o[j] = f2h_bits(v[j]);
    reinterpret_cast<u16x4*>(w)[i] = o;
  }
}

__global__ void conv_f16_kernel(const float* __restrict__ in,
                                unsigned short* __restrict__ out, int n4) {
  int i = blockIdx.x * blockDim.x + threadIdx.x;
  const int stride = gridDim.x * blockDim.x;
  for (; i < n4; i += stride) {
    f32x4 v = reinterpret_cast<const f32x4*>(in)[i];
    u16x4 o;
#pragma unroll
    for (int j = 0; j < 4; ++j) o[j] = f2h_bits(v[j]);
    reinterpret_cast<u16x4*>(out)[i] = o;
  }
}

// ---------------- 256x256 GEMM, BK=32, 4-buffer ring, deep-prefetch ----------------
// C[M,N] = A[M,2048] * B[N,2048]^T ; A/B fp16, C fp32.
// LDS: 4 buffers x 32KB (A 16K + B 16K), subtile = 1KB = [16 rows][32 k] fp16.
// Pipeline: tile tau = 2 phases. p0: ds_read A03+B, stage tile tau+3 (4 loads/wave).
// p1: ds_read A47, vmcnt(8) (keeps tiles tau+2,tau+3 in flight; drains tau+1,
// issued 5 phases earlier ~ HBM latency). Stage into buf b is always >=1 barrier
// after buf b's last reads were consumed (formally race-free).
// SPLIT: hi/lo K-segments spread across 2x blocks (GEMM1 machine fill).

#define FENCE() asm volatile("" ::: "memory")
#define BAR() do { FENCE(); __builtin_amdgcn_s_barrier(); FENCE(); } while (0)
#define VM8() do { FENCE(); asm volatile("s_waitcnt vmcnt(8)" ::: "memory"); } while (0)

template <int MB>
__device__ __forceinline__ void mfma_blk(f32x4 (&acc)[8][4], const f16x8 (&Av)[4],
                                         const f16x8 (&Bv)[4]) {
  __builtin_amdgcn_s_setprio(1);
#pragma unroll
  for (int m = 0; m < 4; ++m)
#pragma unroll
    for (int n = 0; n < 4; ++n)
      acc[MB + m][n] =
          __builtin_amdgcn_mfma_f32_16x16x32_f16(Av[m], Bv[n], acc[MB + m][n], 0, 0, 0);
  __builtin_amdgcn_s_setprio(0);
}

__device__ __forceinline__ void load4(f16x8 (&dst)[4], const char* base) {
#pragma unroll
  for (int m = 0; m < 4; ++m)
    dst[m] = *reinterpret_cast<const f16x8*>(base + m * 1024);
}

__device__ __forceinline__ void stage_tile(const unsigned short* gA,
                                           const unsigned short* gB, int m0, int n0,
                                           int k0, char* buf, int wid, int lane) {
  // source-lane involution matching the LDS read swizzle
  const int sl = lane ^ ((lane >> 4) & 1) ^ (((lane >> 5) & 1) << 1);
  const int rr = sl >> 2;
  const int kc = (sl & 3) * 8;
#pragma unroll
  for (int i = 0; i < 2; ++i) {
    const int c = wid * 2 + i;
    const unsigned short* sA = gA + (size_t)(m0 + c * 16 + rr) * 2048 + (k0 + kc);
    __builtin_amdgcn_global_load_lds(
        (__attribute__((address_space(1))) void*)sA,
        (__attribute__((address_space(3))) void*)(buf + c * 1024), 16, 0, 0);
    const unsigned short* sB = gB + (size_t)(n0 + c * 16 + rr) * 2048 + (k0 + kc);
    __builtin_amdgcn_global_load_lds(
        (__attribute__((address_space(1))) void*)sB,
        (__attribute__((address_space(3))) void*)(buf + 16384 + c * 1024), 16, 0, 0);
  }
}

template <int N, bool EPI, bool NFAST, bool SPLIT>
__global__ void __launch_bounds__(512, 2)
gemm256(const unsigned short* __restrict__ Ahi, const unsigned short* __restrict__ Alo,
        const unsigned short* __restrict__ B, float* __restrict__ C0,
        float* __restrict__ C1, const float* __restrict__ resid,
        const float* __restrict__ gam) {
  constexpr int NT = 64;               // K-tiles (BK=32, K=2048); NT%4==0
  constexpr int MT = MTOT / 256;       // 96
  constexpr int NXT = N / 256;
  constexpr int NWGb = MT * NXT;
  constexpr int NWG = SPLIT ? 2 * NWGb : NWGb;
  constexpr int CPX = NWG / 8;
  __shared__ char lds[131072];

  const int bid = blockIdx.x;
  const int wg = (bid & 7) * CPX + (bid >> 3);   // XCD swizzle (NWG%8==0)
  const int seg = SPLIT ? (wg >= NWGb ? 1 : 0) : 0;
  const int w2 = wg - seg * NWGb;
  const int bx = NFAST ? (w2 % NXT) : (w2 / MT);
  const int by = NFAST ? (w2 / NXT) : (w2 % MT);
  const int m0 = by * 256, n0 = bx * 256;
  const unsigned short* A = seg ? Alo : Ahi;
  float* C = seg ? C1 : C0;

  const int t = threadIdx.x;
  const int lane = t & 63;
  const int wid = t >> 6;
  const int wr = wid >> 2, wc = wid & 3;
  const int laneOff = (lane & 15) * 64 + (lane >> 4) * 16;
  const int swzOff = laneOff ^ (((laneOff >> 9) & 1) << 5) ^ (((laneOff >> 8) & 1) << 4);
  const int aOff = wr * 8192 + swzOff;           // A03 base within a buffer
  const int bOff = 16384 + wc * 4096 + swzOff;   // B base within a buffer

  f32x4 acc[8][4] = {};
  f16x8 A03[4], A47[4], Be[4], Bo[4];

#define WRAPT(TT) ((TT) >= NT ? (TT) - NT : (TT))
#define STAGE(TT) stage_tile(A, B, m0, n0, WRAPT(TT) * 32, lds + ((TT) & 3) * 32768, wid, lane)

  // prologue: stage tiles 0,1,2 (12 loads/wave); drain tile 0, keep {1,2}=8
  STAGE(0);
  STAGE(1);
  STAGE(2);
  VM8();
  BAR();

#define PH0(TAU, BREG, DOMF, BPREV) do { \
    char* bufc = lds + ((TAU) & 3) * 32768; \
    load4(A03, bufc + aOff); \
    load4(BREG, bufc + bOff); \
    STAGE((TAU) + 3); \
    BAR(); \
    if (DOMF) mfma_blk<4>(acc, A47, BPREV); \
    BAR(); \
  } while (0)
#define PH1(TAU, BREG) do { \
    char* bufc = lds + ((TAU) & 3) * 32768; \
    load4(A47, bufc + aOff + 4096); \
    VM8(); \
    BAR(); \
    mfma_blk<0>(acc, A03, BREG); \
    BAR(); \
  } while (0)

  PH0(0, Be, false, Bo);
  PH1(0, Be);
  PH0(1, Bo, true, Be);
  PH1(1, Bo);
  for (int tau = 2; tau < NT; tau += 2) {
    PH0(tau, Be, true, Bo);
    PH1(tau, Be);
    PH0(tau + 1, Bo, true, Be);
    PH1(tau + 1, Bo);
  }
  mfma_blk<4>(acc, A47, Bo);   // trailing quadrant of last (odd) tile

#undef PH0
#undef PH1
#undef STAGE
#undef WRAPT

  // epilogue: C/D layout col = lane&15, row = (lane>>4)*4 + j
  const float g = EPI ? gam[0] : 0.f;
#pragma unroll
  for (int m = 0; m < 8; ++m)
#pragma unroll
    for (int n = 0; n < 4; ++n)
#pragma unroll
      for (int j = 0; j < 4; ++j) {
        const int r = m0 + wr * 128 + m * 16 + (lane >> 4) * 4 + j;
        const int c = n0 + wc * 64 + n * 16 + (lane & 15);
        const size_t idx = (size_t)r * (size_t)N + (size_t)c;
        float v = acc[m][n][j];
        if (EPI) v = g * v + resid[idx];
        C[idx] = v;
      }
}

// ---------------- per-batch: energy -> softmax -> attn out + y = attn@x ----------------
__global__ void __launch_bounds__(256)
attn_fuse(const float* __restrict__ QK1,        // hi-seg partial [MTOT, 512]
          const float* __restrict__ QK2,        // lo-seg partial [MTOT, 512]
          const unsigned short* __restrict__ xh, // [MTOT, 2048] fp16
          float* __restrict__ attn_out,          // [NB, 36]
          unsigned short* __restrict__ y)        // [MTOT, 2048] fp16
{
  __shared__ float qk[NS * 512];
  __shared__ float eng[36];
  __shared__ float att[36];
  const int b = blockIdx.x;
  const int t = threadIdx.x;
  {
    const f32x4* s1 = reinterpret_cast<const f32x4*>(QK1 + (size_t)b * (NS * 512));
    const f32x4* s2 = reinterpret_cast<const f32x4*>(QK2 + (size_t)b * (NS * 512));
    f32x4* dst = reinterpret_cast<f32x4*>(qk);
    for (int i = t; i < (NS * 512) / 4; i += 256) dst[i] = s1[i] + s2[i];
  }
  __syncthreads();
  if (t < 144) {
    const int s = t / 24;
    const int rem = t - s * 24;
    const int u = rem >> 2;
    const int sub = rem & 3;
    const float* qr = qk + s * 512;
    const float* kr = qk + u * 512 + 256;
    float sum = 0.f;
    const int d0 = sub * 64;
#pragma unroll 4
    for (int d = 0; d < 64; ++d) sum += qr[d0 + d] * kr[d0 + d];
    sum += __shfl_xor(sum, 1);
    sum += __shfl_xor(sum, 2);
    if (sub == 0) eng[s * 6 + u] = sum;
  }
  __syncthreads();
  if (t < 6) {
    float e[6];
#pragma unroll
    for (int u = 0; u < 6; ++u) e[u] = eng[t * 6 + u];
    float mx = e[0];
#pragma unroll
    for (int u = 1; u < 6; ++u) mx = fmaxf(mx, e[u]);
    float p[6];
    float sm = 0.f;
#pragma unroll
    for (int u = 0; u < 6; ++u) { p[u] = expf(e[u] - mx); sm += p[u]; }
    const float inv = 1.0f / sm;
#pragma unroll
    for (int u = 0; u < 6; ++u) {
      const float a = p[u] * inv;
      att[t * 6 + u] = a;
      attn_out[(size_t)b * 36 + t * 6 + u] = a;
    }
  }
  __syncthreads();
  const unsigned short* xb = xh + (size_t)b * (NS * NC);
  unsigned short* yb = y + (size_t)b * (NS * NC);
  const int c0 = t * 8;
  f32x4 xv[12];
#pragma unroll
  for (int u = 0; u < 6; ++u) {
    u16x8 v = *reinterpret_cast<const u16x8*>(xb + u * NC + c0);
#pragma unroll
    for (int j = 0; j < 4; ++j) {
      xv[2 * u][j] = h2f(v[j]);
      xv[2 * u + 1][j] = h2f(v[4 + j]);
    }
  }
#pragma unroll
  for (int s = 0; s < 6; ++s) {
    f32x4 a0 = 0.f, a1 = 0.f;
#pragma unroll
    for (int u = 0; u < 6; ++u) {
      const float w = att[s * 6 + u];
      a0 += w * xv[2 * u];
      a1 += w * xv[2 * u + 1];
    }
    u16x8 o;
#pragma unroll
    for (int j = 0; j < 4; ++j) { o[j] = f2h_bits(a0[j]); o[4 + j] = f2h_bits(a1[j]); }
    *reinterpret_cast<u16x8*>(yb + s * NC + c0) = o;
  }
}

extern "C" void kernel_launch(void* const* d_in, const int* in_sizes, int n_in,
                              void* d_out, int out_size, void* d_ws, size_t ws_size,
                              hipStream_t stream) {
  (void)in_sizes; (void)n_in; (void)out_size; (void)ws_size;
  const float* x   = (const float*)d_in[0];
  const float* Wq  = (const float*)d_in[1];
  const float* Wk  = (const float*)d_in[2];
  const float* Wv  = (const float*)d_in[3];
  const float* gam = (const float*)d_in[4];
  float* out = (float*)d_out;
  float* attn_out = out + (size_t)MTOT * NC;

  char* ws = (char*)d_ws;
  unsigned short* xh  = (unsigned short*)(ws);                    // 100663296 B
  unsigned short* xl  = (unsigned short*)(ws + 100663296ull);     // 100663296 B (reused as y)
  unsigned short* wqk = (unsigned short*)(ws + 201326592ull);     // 2097152 B
  unsigned short* wvh = (unsigned short*)(ws + 203423744ull);     // 8388608 B
  float*          qkb = (float*)(ws + 211812352ull);              // 50331648 B
  float*          qk2 = out;  // lo-seg partial parked in d_out (overwritten by GEMM2)

  split_x_kernel<<<2048, 256, 0, stream>>>(x, xh, xl, MTOT * NC / 4);
  prep_wqk_kernel<<<256, 256, 0, stream>>>(Wq, Wk, wqk);
  conv_f16_kernel<<<512, 256, 0, stream>>>(Wv, wvh, NC * NC / 4);

  // QK partials: seg0 = x_hi @ W^T -> qkb ; seg1 = x_lo @ W^T -> qk2 (384 blocks)
  gemm256<512, false, false, true><<<384, 512, 0, stream>>>(
      xh, xl, wqk, qkb, qk2, nullptr, nullptr);

  // energies (sum of partials) + softmax + attention output + y = attn @ x
  attn_fuse<<<NB, 256, 0, stream>>>(qkb, qk2, xh, attn_out, xl);

  // out = gamma * (y @ Wv^T) + x    (n-fast block order for y L2 reuse)
  gemm256<2048, true, true, false><<<768, 512, 0, stream>>>(
      xl, nullptr, wvh, out, nullptr, x, gam);
}

// Round 9
// 421.051 us; speedup vs baseline: 1.3064x; 1.3064x over previous
//
#include <hip/hip_runtime.h>

typedef __attribute__((ext_vector_type(4))) float f32x4;
typedef __attribute__((ext_vector_type(8))) _Float16 f16x8;
typedef __attribute__((ext_vector_type(4))) unsigned short u16x4;
typedef __attribute__((ext_vector_type(8))) unsigned short u16x8;

#define NB 4096
#define NS 6
#define NC 2048
#define MTOT (NB * NS)   // 24576

static __device__ __forceinline__ unsigned short f2h_bits(float f) {
  _Float16 h = (_Float16)f;
  unsigned short b;
  __builtin_memcpy(&b, &h, 2);
  return b;
}
static __device__ __forceinline__ float h2f(unsigned short b) {
  _Float16 h;
  __builtin_memcpy(&h, &b, 2);
  return (float)h;
}

// ---------------- prep: fp32 -> fp16 ----------------
__global__ void conv_f16_kernel(const float* __restrict__ in,
                                unsigned short* __restrict__ out, int n4) {
  int i = blockIdx.x * blockDim.x + threadIdx.x;
  const int stride = gridDim.x * blockDim.x;
  for (; i < n4; i += stride) {
    f32x4 v = reinterpret_cast<const f32x4*>(in)[i];
    u16x4 o;
#pragma unroll
    for (int j = 0; j < 4; ++j) o[j] = f2h_bits(v[j]);
    reinterpret_cast<u16x4*>(out)[i] = o;
  }
}

// ------------- prep: [Wq;Wk] stacked -> fp16, 512 x 2048 -------------
__global__ void prep_wqk_kernel(const float* __restrict__ Wq,
                                const float* __restrict__ Wk,
                                unsigned short* __restrict__ w) {
  int i = blockIdx.x * blockDim.x + threadIdx.x;
  const int stride = gridDim.x * blockDim.x;
  for (; i < 262144; i += stride) {
    const int row = i >> 9;
    const int col4 = i & 511;
    const float* src = (row < 256) ? (Wq + (size_t)row * NC)
                                   : (Wk + (size_t)(row - 256) * NC);
    f32x4 v = reinterpret_cast<const f32x4*>(src)[col4];
    u16x4 o;
#pragma unroll
    for (int j = 0; j < 4; ++j) o[j] = f2h_bits(v[j]);
    reinterpret_cast<u16x4*>(w)[i] = o;
  }
}

// ---------------- 256x256 8-phase GEMM (fp16 inputs) ----------------
// C[M,N] = sum_seg A_seg[M,2048] * B_seg[N,2048]^T ; A/B fp16, C fp32.
// Round-7 structure (best measured: 492us total): LDS 2 buf x (A 32KB + B 32KB),
// subtile = 1KB = [16 rows][32 k]. Raw s_barrier + counted vmcnt(4) once per
// tile; staging WRAPS mod NT so the outstanding-load ledger is exact at the tail.
// NFAST: n-fast block order (XCD panel-group L2 reuse on GEMM2's y re-reads).

#define FENCE() asm volatile("" ::: "memory")
#define BAR() do { FENCE(); __builtin_amdgcn_s_barrier(); FENCE(); } while (0)
#define VM4BAR() do { FENCE(); asm volatile("s_waitcnt vmcnt(4)" ::: "memory"); \
                      __builtin_amdgcn_s_barrier(); FENCE(); } while (0)

template <int MB>
__device__ __forceinline__ void mfma_blk(f32x4 (&acc)[8][4], const f16x8 (&Av)[4],
                                         const f16x8 (&Bv)[4]) {
  __builtin_amdgcn_s_setprio(1);
#pragma unroll
  for (int m = 0; m < 4; ++m)
#pragma unroll
    for (int n = 0; n < 4; ++n)
      acc[MB + m][n] =
          __builtin_amdgcn_mfma_f32_16x16x32_f16(Av[m], Bv[n], acc[MB + m][n], 0, 0, 0);
  __builtin_amdgcn_s_setprio(0);
}

__device__ __forceinline__ void load4(f16x8 (&dst)[4], const char* base, int kk) {
#pragma unroll
  for (int m = 0; m < 4; ++m)
    dst[m] = *reinterpret_cast<const f16x8*>(base + (m * 2 + kk) * 1024);
}

__device__ __forceinline__ void stage_op(const unsigned short* g, int row0, int k0,
                                         char* ldsOp, int wid, int lane) {
  const int sl = lane ^ ((lane >> 4) & 1) ^ (((lane >> 5) & 1) << 1);
#pragma unroll
  for (int h = 0; h < 2; ++h)
#pragma unroll
    for (int i = 0; i < 2; ++i) {
      const int c = wid * 2 + i;
      const unsigned short* src =
          g + (size_t)(row0 + h * 128 + (c >> 1) * 16 + (sl >> 2)) * 2048 +
          (unsigned)(k0 + (c & 1) * 32 + (sl & 3) * 8);
      __builtin_amdgcn_global_load_lds(
          (__attribute__((address_space(1))) void*)src,
          (__attribute__((address_space(3))) void*)(ldsOp + h * 16384 + c * 1024),
          16, 0, 0);
    }
}

template <int NSEG, int N, bool EPI, bool NFAST>
__global__ void __launch_bounds__(512, 2)
gemm256(const unsigned short* __restrict__ A0, const unsigned short* __restrict__ B0,
        const unsigned short* __restrict__ A1, const unsigned short* __restrict__ B1,
        float* __restrict__ C, const float* __restrict__ resid,
        const float* __restrict__ gam) {
  constexpr int NTPS = 2048 / 64;       // K-tiles per segment (32)
  constexpr int NT = NSEG * NTPS;       // total K-tiles (even)
  constexpr int MT = MTOT / 256;        // 96
  constexpr int NXT = N / 256;
  constexpr int NWG = MT * NXT;
  constexpr int CPX = NWG / 8;
  __shared__ char lds[131072];

  const int bid = blockIdx.x;
  const int wg = (bid & 7) * CPX + (bid >> 3);   // XCD swizzle (NWG%8==0)
  const int bx = NFAST ? (wg % NXT) : (wg / MT);
  const int by = NFAST ? (wg / NXT) : (wg % MT);
  const int m0 = by * 256, n0 = bx * 256;

  const int t = threadIdx.x;
  const int lane = t & 63;
  const int wid = t >> 6;
  const int wr = wid >> 2, wc = wid & 3;
  const int laneOff = (lane & 15) * 64 + (lane >> 4) * 16;
  const int swzOff = laneOff ^ (((laneOff >> 9) & 1) << 5) ^ (((laneOff >> 8) & 1) << 4);

  f32x4 acc[8][4] = {};
  f16x8 A03[4], A47[4], Bk0[4], Bk1[4];

  const int aBase = wr * 16384 + swzOff;
  const int bBase = 32768 + (wc >> 1) * 16384 + (wc & 1) * 8192 + swzOff;

#define SEL(P0, P1, S) ((NSEG == 1) ? (P0) : ((S) == 0 ? (P0) : (P1)))
#define WRAPT(TT) ((TT) >= NT ? (TT) - NT : (TT))
#define STAGE_A(TT) do { int tw_ = WRAPT(TT); int s_ = tw_ / NTPS; \
    stage_op(SEL(A0, A1, s_), m0, (tw_ % NTPS) * 64, lds + ((TT) & 1) * 65536, wid, lane); } while (0)
#define STAGE_B(TT) do { int tw_ = WRAPT(TT); int s_ = tw_ / NTPS; \
    stage_op(SEL(B0, B1, s_), n0, (tw_ % NTPS) * 64, lds + ((TT) & 1) * 65536 + 32768, wid, lane); } while (0)

  // prologue: tile0 A+B, tile1 B; drain tile0, leave tile1-B in flight
  STAGE_A(0);
  STAGE_B(0);
  STAGE_B(1);
  VM4BAR();

#define TILE(TAU, FIRST) do { \
    char* bufc = lds + ((TAU) & 1) * 65536; \
    /* p0 */ \
    load4(A03, bufc + aBase, 0); \
    load4(Bk0, bufc + bBase, 0); \
    STAGE_A((TAU) + 1); \
    BAR(); \
    if (!(FIRST)) mfma_blk<4>(acc, A47, Bk1); \
    BAR(); \
    /* p1 */ \
    load4(A47, bufc + aBase + 8192, 0); \
    BAR(); \
    mfma_blk<0>(acc, A03, Bk0); \
    BAR(); \
    /* p2 */ \
    load4(A03, bufc + aBase, 1); \
    load4(Bk1, bufc + bBase, 1); \
    BAR(); \
    mfma_blk<4>(acc, A47, Bk0); \
    BAR(); \
    /* p3 */ \
    load4(A47, bufc + aBase + 8192, 1); \
    STAGE_B((TAU) + 2); \
    VM4BAR(); \
    mfma_blk<0>(acc, A03, Bk1); \
    BAR(); \
  } while (0)

  TILE(0, 1);
  for (int tau = 1; tau < NT; ++tau) TILE(tau, 0);
  mfma_blk<4>(acc, A47, Bk1);   // trailing quadrant of last tile

#undef TILE
#undef STAGE_A
#undef STAGE_B
#undef WRAPT
#undef SEL

  // epilogue: C/D layout col = lane&15, row = (lane>>4)*4 + j
  const float g = EPI ? gam[0] : 0.f;
#pragma unroll
  for (int m = 0; m < 8; ++m)
#pragma unroll
    for (int n = 0; n < 4; ++n)
#pragma unroll
      for (int j = 0; j < 4; ++j) {
        const int r = m0 + wr * 128 + m * 16 + (lane >> 4) * 4 + j;
        const int c = n0 + wc * 64 + n * 16 + (lane & 15);
        const size_t idx = (size_t)r * (size_t)N + (size_t)c;
        float v = acc[m][n][j];
        if (EPI) v = g * v + resid[idx];
        C[idx] = v;
      }
}

// ---------------- per-batch: energy -> softmax -> attn out + y = attn@x ----------------
__global__ void __launch_bounds__(256)
attn_fuse(const float* __restrict__ QK,          // [MTOT, 512] cols 0..255=q, 256..511=k
          const unsigned short* __restrict__ xh, // [MTOT, 2048] fp16
          float* __restrict__ attn_out,          // [NB, 36]
          unsigned short* __restrict__ y)        // [MTOT, 2048] fp16
{
  __shared__ float qk[NS * 512];
  __shared__ float eng[36];
  __shared__ float att[36];
  const int b = blockIdx.x;
  const int t = threadIdx.x;
  {
    const f32x4* src = reinterpret_cast<const f32x4*>(QK + (size_t)b * (NS * 512));
    f32x4* dst = reinterpret_cast<f32x4*>(qk);
    for (int i = t; i < (NS * 512) / 4; i += 256) dst[i] = src[i];
  }
  __syncthreads();
  if (t < 144) {
    const int s = t / 24;
    const int rem = t - s * 24;
    const int u = rem >> 2;
    const int sub = rem & 3;
    const float* qr = qk + s * 512;
    const float* kr = qk + u * 512 + 256;
    float sum = 0.f;
    const int d0 = sub * 64;
#pragma unroll 4
    for (int d = 0; d < 64; ++d) sum += qr[d0 + d] * kr[d0 + d];
    sum += __shfl_xor(sum, 1);
    sum += __shfl_xor(sum, 2);
    if (sub == 0) eng[s * 6 + u] = sum;
  }
  __syncthreads();
  if (t < 6) {
    float e[6];
#pragma unroll
    for (int u = 0; u < 6; ++u) e[u] = eng[t * 6 + u];
    float mx = e[0];
#pragma unroll
    for (int u = 1; u < 6; ++u) mx = fmaxf(mx, e[u]);
    float p[6];
    float sm = 0.f;
#pragma unroll
    for (int u = 0; u < 6; ++u) { p[u] = expf(e[u] - mx); sm += p[u]; }
    const float inv = 1.0f / sm;
#pragma unroll
    for (int u = 0; u < 6; ++u) {
      const float a = p[u] * inv;
      att[t * 6 + u] = a;
      attn_out[(size_t)b * 36 + t * 6 + u] = a;
    }
  }
  __syncthreads();
  const unsigned short* xb = xh + (size_t)b * (NS * NC);
  unsigned short* yb = y + (size_t)b * (NS * NC);
  const int c0 = t * 8;
  f32x4 xv[12];
#pragma unroll
  for (int u = 0; u < 6; ++u) {
    u16x8 v = *reinterpret_cast<const u16x8*>(xb + u * NC + c0);
#pragma unroll
    for (int j = 0; j < 4; ++j) {
      xv[2 * u][j] = h2f(v[j]);
      xv[2 * u + 1][j] = h2f(v[4 + j]);
    }
  }
#pragma unroll
  for (int s = 0; s < 6; ++s) {
    f32x4 a0 = 0.f, a1 = 0.f;
#pragma unroll
    for (int u = 0; u < 6; ++u) {
      const float w = att[s * 6 + u];
      a0 += w * xv[2 * u];
      a1 += w * xv[2 * u + 1];
    }
    u16x8 o;
#pragma unroll
    for (int j = 0; j < 4; ++j) { o[j] = f2h_bits(a0[j]); o[4 + j] = f2h_bits(a1[j]); }
    *reinterpret_cast<u16x8*>(yb + s * NC + c0) = o;
  }
}

extern "C" void kernel_launch(void* const* d_in, const int* in_sizes, int n_in,
                              void* d_out, int out_size, void* d_ws, size_t ws_size,
                              hipStream_t stream) {
  (void)in_sizes; (void)n_in; (void)out_size; (void)ws_size;
  const float* x   = (const float*)d_in[0];
  const float* Wq  = (const float*)d_in[1];
  const float* Wk  = (const float*)d_in[2];
  const float* Wv  = (const float*)d_in[3];
  const float* gam = (const float*)d_in[4];
  float* out = (float*)d_out;
  float* attn_out = out + (size_t)MTOT * NC;

  char* ws = (char*)d_ws;
  unsigned short* xh  = (unsigned short*)(ws);                    // 100663296 B
  unsigned short* yb  = (unsigned short*)(ws + 100663296ull);     // 100663296 B (y)
  unsigned short* wqk = (unsigned short*)(ws + 201326592ull);     // 2097152 B
  unsigned short* wvh = (unsigned short*)(ws + 203423744ull);     // 8388608 B
  float*          qkb = (float*)(ws + 211812352ull);              // 50331648 B

  conv_f16_kernel<<<2048, 256, 0, stream>>>(x, xh, MTOT * NC / 4);
  prep_wqk_kernel<<<256, 256, 0, stream>>>(Wq, Wk, wqk);
  conv_f16_kernel<<<512, 256, 0, stream>>>(Wv, wvh, NC * NC / 4);

  // QK = x @ [Wq;Wk]^T, single-pass fp16 (error ~3e-3 on energies, thr 0.02)
  gemm256<1, 512, false, false><<<192, 512, 0, stream>>>(
      xh, wqk, nullptr, nullptr, qkb, nullptr, nullptr);

  // energies + softmax + attention output + y = attn @ x
  attn_fuse<<<NB, 256, 0, stream>>>(qkb, xh, attn_out, yb);

  // out = gamma * (y @ Wv^T) + x    (n-fast block order for y L2 reuse)
  gemm256<1, 2048, true, true><<<768, 512, 0, stream>>>(
      yb, wvh, nullptr, nullptr, out, x, gam);
}